// Round 1
// baseline (691.661 us; speedup 1.0000x reference)
//
#include <hip/hip_runtime.h>
#include <cmath>

// Problem constants
#define B_ 2
#define NQ_ 900
#define C_ 256
#define H_ 8
#define N_ 4096
#define DH_ 32

// ---------------------------------------------------------------------------
// Generic fp32 GEMM: Y[M,256] = (X[M,256] @ W[256,256] + bias[256]) * alpha
// 64x64 tile per 256-thread block, BK=16, 4x4 micro-tile per thread.
// ---------------------------------------------------------------------------
__global__ __launch_bounds__(256) void gemm_bias_kernel(
    const float* __restrict__ X, const float* __restrict__ W,
    const float* __restrict__ bias, float* __restrict__ Y,
    int M, float alpha)
{
    __shared__ float As[16][65];   // [k][m], padded to kill store conflicts
    __shared__ float Bs[16][64];   // [k][n]
    const int tid = threadIdx.x;
    const int tx = tid & 15, ty = tid >> 4;
    const int m0 = blockIdx.x * 64;
    const int n0 = blockIdx.y * 64;

    const int arow = tid >> 2, acol4 = tid & 3;   // A loader mapping
    const int brow = tid >> 4, bcol4 = tid & 15;  // B loader mapping

    float acc[4][4] = {};

    for (int k0 = 0; k0 < 256; k0 += 16) {
        float4 av = make_float4(0.f, 0.f, 0.f, 0.f);
        if (m0 + arow < M)
            av = *(const float4*)(X + (size_t)(m0 + arow) * 256 + k0 + acol4 * 4);
        As[acol4 * 4 + 0][arow] = av.x;
        As[acol4 * 4 + 1][arow] = av.y;
        As[acol4 * 4 + 2][arow] = av.z;
        As[acol4 * 4 + 3][arow] = av.w;

        float4 bv = *(const float4*)(W + (size_t)(k0 + brow) * 256 + n0 + bcol4 * 4);
        *(float4*)(&Bs[brow][bcol4 * 4]) = bv;

        __syncthreads();
        #pragma unroll
        for (int k = 0; k < 16; ++k) {
            float4 b4 = *(const float4*)(&Bs[k][tx * 4]);
            #pragma unroll
            for (int i = 0; i < 4; ++i) {
                float a = As[k][ty * 4 + i];
                acc[i][0] = fmaf(a, b4.x, acc[i][0]);
                acc[i][1] = fmaf(a, b4.y, acc[i][1]);
                acc[i][2] = fmaf(a, b4.z, acc[i][2]);
                acc[i][3] = fmaf(a, b4.w, acc[i][3]);
            }
        }
        __syncthreads();
    }

    #pragma unroll
    for (int i = 0; i < 4; ++i) {
        int mrow = m0 + ty * 4 + i;
        if (mrow < M) {
            int n = n0 + tx * 4;
            float4 o;
            o.x = (acc[i][0] + bias[n + 0]) * alpha;
            o.y = (acc[i][1] + bias[n + 1]) * alpha;
            o.z = (acc[i][2] + bias[n + 2]) * alpha;
            o.w = (acc[i][3] + bias[n + 3]) * alpha;
            *(float4*)(Y + (size_t)mrow * 256 + n) = o;
        }
    }
}

// ---------------------------------------------------------------------------
// RPE MLP: one thread per (b, q, pos). Computes both the x-axis and y-axis
// MLP (2 -> 512 relu -> 8). Outputs rpe_x/rpe_y laid out [b][q][pos][h].
// ---------------------------------------------------------------------------
__global__ __launch_bounds__(256) void rpe_kernel(
    const float* __restrict__ ref2d,
    const float* __restrict__ W1x, const float* __restrict__ b1x, const float* __restrict__ W2x,
    const float* __restrict__ W1y, const float* __restrict__ b1y, const float* __restrict__ W2y,
    float* __restrict__ rpe_x, float* __restrict__ rpe_y)
{
    __shared__ float sW1x[1024], sb1x[512], sW2x[4096];
    __shared__ float sW1y[1024], sb1y[512], sW2y[4096];
    const int tid = threadIdx.x;
    for (int i = tid; i < 1024; i += 256) { sW1x[i] = W1x[i]; sW1y[i] = W1y[i]; }
    for (int i = tid; i < 512;  i += 256) { sb1x[i] = b1x[i]; sb1y[i] = b1y[i]; }
    for (int i = tid; i < 4096; i += 256) { sW2x[i] = W2x[i]; sW2y[i] = W2y[i]; }
    __syncthreads();

    const int gid = blockIdx.x * 256 + tid;       // < B*NQ*64 = 115200 exactly
    const int pos = gid & 63;
    const int bq  = gid >> 6;                      // b*900+q
    const float4 r = *(const float4*)(ref2d + (size_t)bq * 4);  // cx, cy, w, h
    const float pc = (pos + 0.5f) * 16.0f;
    const float dx0 = (r.x - r.z * 0.5f) - pc;
    const float dx1 = (r.x + r.z * 0.5f) - pc;
    const float dy0 = (r.y - r.w * 0.5f) - pc;
    const float dy1 = (r.y + r.w * 0.5f) - pc;

    float ax[8] = {}, ay[8] = {};
    for (int j = 0; j < 512; ++j) {
        float hx = fmaf(dx0, sW1x[j], fmaf(dx1, sW1x[512 + j], sb1x[j]));
        float hy = fmaf(dy0, sW1y[j], fmaf(dy1, sW1y[512 + j], sb1y[j]));
        hx = fmaxf(hx, 0.f);
        hy = fmaxf(hy, 0.f);
        #pragma unroll
        for (int t = 0; t < 8; ++t) {
            ax[t] = fmaf(hx, sW2x[j * 8 + t], ax[t]);
            ay[t] = fmaf(hy, sW2y[j * 8 + t], ay[t]);
        }
    }
    #pragma unroll
    for (int t = 0; t < 8; ++t) {
        rpe_x[(size_t)gid * 8 + t] = ax[t];
        rpe_y[(size_t)gid * 8 + t] = ay[t];
    }
}

// ---------------------------------------------------------------------------
// Fused attention: block = (query-tile of 64, head h, batch b).
// 256 threads = 64 queries x 4 key-slices. Each thread keeps an independent
// online-softmax partial (m, l, acc[32]) over its 16-key slice of each
// 64-key chunk; partials are merged at the end (split-softmax merge).
// scores = q.k + rpe_x[col] + rpe_y[row] + mask.
// ---------------------------------------------------------------------------
__global__ __launch_bounds__(256) void attn_kernel(
    const float* __restrict__ q, const float* __restrict__ k, const float* __restrict__ v,
    const float* __restrict__ rpe_x, const float* __restrict__ rpe_y,
    const unsigned char* __restrict__ mask, float* __restrict__ xout)
{
    __shared__ float kv[4096];            // k chunk [64][32] @0, v chunk @2048; reused as ot[64][33]
    __shared__ float rx[64 * 65];         // stride 65: stride-64 would be a 64-way bank conflict
    __shared__ float ry[64 * 65];
    __shared__ float sm[4][64], sl[4][64], smsk[64];

    const int tid = threadIdx.x;
    const int qb = blockIdx.x, h = blockIdx.y, b = blockIdx.z;
    const int q0 = qb * 64;
    const int qi = tid & 63, slice = tid >> 6;

    // q fragment in registers
    float4 qv[8];
    {
        int qq = q0 + qi;
        if (qq < NQ_) {
            const float* qp = q + ((size_t)(b * NQ_ + qq) * 256 + h * 32);
            #pragma unroll
            for (int d = 0; d < 8; ++d) qv[d] = *(const float4*)(qp + d * 4);
        } else {
            #pragma unroll
            for (int d = 0; d < 8; ++d) qv[d] = make_float4(0.f, 0.f, 0.f, 0.f);
        }
    }
    // RPE tiles for this (b, head, query-tile)
    for (int i = tid; i < 4096; i += 256) {
        int qq = q0 + (i >> 6), pos = i & 63;
        float vx = 0.f, vy = 0.f;
        if (qq < NQ_) {
            size_t base = ((size_t)(b * NQ_ + qq) * 64 + pos) * 8 + h;
            vx = rpe_x[base];
            vy = rpe_y[base];
        }
        rx[(i >> 6) * 65 + pos] = vx;
        ry[(i >> 6) * 65 + pos] = vy;
    }

    float m = -INFINITY, l = 0.f;
    float4 acc[8];
    #pragma unroll
    for (int d = 0; d < 8; ++d) acc[d] = make_float4(0.f, 0.f, 0.f, 0.f);

    for (int n0 = 0; n0 < N_; n0 += 64) {
        __syncthreads();   // previous chunk fully consumed before restaging
        #pragma unroll
        for (int r = 0; r < 2; ++r) {
            int i = tid + r * 256;          // 0..511 -> 64 keys x 8 float4
            int key = i >> 3, d4 = i & 7;
            size_t g = ((size_t)(b * N_ + n0 + key) * 256 + h * 32 + d4 * 4);
            *(float4*)(&kv[key * 32 + d4 * 4])        = *(const float4*)(k + g);
            *(float4*)(&kv[2048 + key * 32 + d4 * 4]) = *(const float4*)(v + g);
        }
        if (tid < 64) smsk[tid] = mask[(size_t)b * N_ + n0 + tid] ? -100.0f : 0.0f;
        __syncthreads();

        float sc[16];
        float cmax = -INFINITY;
        #pragma unroll
        for (int j = 0; j < 16; ++j) {
            int kk = slice * 16 + j;
            const float4* kp = (const float4*)(&kv[kk * 32]);
            float s = 0.f;
            #pragma unroll
            for (int d = 0; d < 8; ++d) {
                float4 kd = kp[d];
                s = fmaf(qv[d].x, kd.x, s);
                s = fmaf(qv[d].y, kd.y, s);
                s = fmaf(qv[d].z, kd.z, s);
                s = fmaf(qv[d].w, kd.w, s);
            }
            int n = n0 + kk;
            s += rx[qi * 65 + (n & 63)] + ry[qi * 65 + (n >> 6)] + smsk[kk];
            sc[j] = s;
            cmax = fmaxf(cmax, s);
        }
        float mnew = fmaxf(m, cmax);
        float alpha = __expf(m - mnew);    // first chunk: exp(-inf)=0, safe
        l *= alpha;
        #pragma unroll
        for (int d = 0; d < 8; ++d) {
            acc[d].x *= alpha; acc[d].y *= alpha; acc[d].z *= alpha; acc[d].w *= alpha;
        }
        #pragma unroll
        for (int j = 0; j < 16; ++j) {
            int kk = slice * 16 + j;
            float p = __expf(sc[j] - mnew);
            l += p;
            const float4* vp = (const float4*)(&kv[2048 + kk * 32]);
            #pragma unroll
            for (int d = 0; d < 8; ++d) {
                float4 vd = vp[d];
                acc[d].x = fmaf(p, vd.x, acc[d].x);
                acc[d].y = fmaf(p, vd.y, acc[d].y);
                acc[d].z = fmaf(p, vd.z, acc[d].z);
                acc[d].w = fmaf(p, vd.w, acc[d].w);
            }
        }
        m = mnew;
    }

    __syncthreads();                      // all kv reads done before reuse
    sm[slice][qi] = m;
    sl[slice][qi] = l;
    __syncthreads();

    float mg = fmaxf(fmaxf(sm[0][qi], sm[1][qi]), fmaxf(sm[2][qi], sm[3][qi]));
    float lg = sl[0][qi] * __expf(sm[0][qi] - mg) + sl[1][qi] * __expf(sm[1][qi] - mg)
             + sl[2][qi] * __expf(sm[2][qi] - mg) + sl[3][qi] * __expf(sm[3][qi] - mg);
    float wgt = __expf(m - mg) / lg;

    float* ot = kv;                       // reuse as [64][33]
    for (int s = 0; s < 4; ++s) {
        if (slice == s) {
            #pragma unroll
            for (int d = 0; d < 8; ++d) {
                int base = qi * 33 + d * 4;
                if (s == 0) {
                    ot[base + 0] = wgt * acc[d].x;
                    ot[base + 1] = wgt * acc[d].y;
                    ot[base + 2] = wgt * acc[d].z;
                    ot[base + 3] = wgt * acc[d].w;
                } else {
                    ot[base + 0] += wgt * acc[d].x;
                    ot[base + 1] += wgt * acc[d].y;
                    ot[base + 2] += wgt * acc[d].z;
                    ot[base + 3] += wgt * acc[d].w;
                }
            }
        }
        __syncthreads();
    }

    for (int i = tid; i < 2048; i += 256) {
        int qi2 = i >> 5, d = i & 31;
        int qq = q0 + qi2;
        if (qq < NQ_)
            xout[(size_t)(b * NQ_ + qq) * 256 + h * 32 + d] = ot[qi2 * 33 + d];
    }
}

// ---------------------------------------------------------------------------
extern "C" void kernel_launch(void* const* d_in, const int* in_sizes, int n_in,
                              void* d_out, int out_size, void* d_ws, size_t ws_size,
                              hipStream_t stream)
{
    const float* query = (const float*)d_in[1];
    const float* ref2d = (const float*)d_in[2];
    const float* kin   = (const float*)d_in[3];
    const float* vin   = (const float*)d_in[4];
    const unsigned char* mask = (const unsigned char*)d_in[6];
    const float* W1x = (const float*)d_in[7];
    const float* b1x = (const float*)d_in[8];
    const float* W2x = (const float*)d_in[9];
    const float* W1y = (const float*)d_in[10];
    const float* b1y = (const float*)d_in[11];
    const float* W2y = (const float*)d_in[12];
    const float* Wq  = (const float*)d_in[13];
    const float* bq  = (const float*)d_in[14];
    const float* Wk  = (const float*)d_in[15];
    const float* bk  = (const float*)d_in[16];
    const float* Wv  = (const float*)d_in[17];
    const float* bv  = (const float*)d_in[18];
    const float* Wp  = (const float*)d_in[19];
    const float* bp  = (const float*)d_in[20];

    float* ws   = (float*)d_ws;
    float* qws  = ws;                          // 1800*256   = 460800
    float* kws  = qws + 460800;                // 8192*256   = 2097152
    float* vws  = kws + 2097152;               // 8192*256   = 2097152
    float* rxws = vws + 2097152;               // 2*900*64*8 = 921600
    float* ryws = rxws + 921600;               // 921600
    float* xws  = ryws + 921600;               // 460800
    float* out  = (float*)d_out;

    const float scale = 1.0f / sqrtf(32.0f);

    gemm_bias_kernel<<<dim3(29, 4),  256, 0, stream>>>(query, Wq, bq, qws, 1800, scale);
    gemm_bias_kernel<<<dim3(128, 4), 256, 0, stream>>>(kin,   Wk, bk, kws, 8192, 1.0f);
    gemm_bias_kernel<<<dim3(128, 4), 256, 0, stream>>>(vin,   Wv, bv, vws, 8192, 1.0f);
    rpe_kernel<<<450, 256, 0, stream>>>(ref2d, W1x, b1x, W2x, W1y, b1y, W2y, rxws, ryws);
    attn_kernel<<<dim3(15, 8, 2), 256, 0, stream>>>(qws, kws, vws, rxws, ryws, mask, xws);
    gemm_bias_kernel<<<dim3(29, 4),  256, 0, stream>>>(xws, Wp, bp, out, 1800, 1.0f);
}

// Round 3
// 395.314 us; speedup vs baseline: 1.7496x; 1.7496x over previous
//
#include <hip/hip_runtime.h>
#include <cmath>

// Problem constants
#define B_ 2
#define NQ_ 900
#define C_ 256
#define H_ 8
#define N_ 4096
#define DH_ 32

// ---------------------------------------------------------------------------
// Generic fp32 GEMM: Y[M,256] = (X[M,256] @ W[256,256] + bias[256]) * alpha
// 64x64 tile per 256-thread block, BK=16, 4x4 micro-tile per thread.
// ---------------------------------------------------------------------------
__global__ __launch_bounds__(256) void gemm_bias_kernel(
    const float* __restrict__ X, const float* __restrict__ W,
    const float* __restrict__ bias, float* __restrict__ Y,
    int M, float alpha)
{
    __shared__ float As[16][65];   // [k][m], padded to kill store conflicts
    __shared__ float Bs[16][64];   // [k][n]
    const int tid = threadIdx.x;
    const int tx = tid & 15, ty = tid >> 4;
    const int m0 = blockIdx.x * 64;
    const int n0 = blockIdx.y * 64;

    const int arow = tid >> 2, acol4 = tid & 3;   // A loader mapping
    const int brow = tid >> 4, bcol4 = tid & 15;  // B loader mapping

    float acc[4][4] = {};

    for (int k0 = 0; k0 < 256; k0 += 16) {
        float4 av = make_float4(0.f, 0.f, 0.f, 0.f);
        if (m0 + arow < M)
            av = *(const float4*)(X + (size_t)(m0 + arow) * 256 + k0 + acol4 * 4);
        As[acol4 * 4 + 0][arow] = av.x;
        As[acol4 * 4 + 1][arow] = av.y;
        As[acol4 * 4 + 2][arow] = av.z;
        As[acol4 * 4 + 3][arow] = av.w;

        float4 bv = *(const float4*)(W + (size_t)(k0 + brow) * 256 + n0 + bcol4 * 4);
        *(float4*)(&Bs[brow][bcol4 * 4]) = bv;

        __syncthreads();
        #pragma unroll
        for (int k = 0; k < 16; ++k) {
            float4 b4 = *(const float4*)(&Bs[k][tx * 4]);
            #pragma unroll
            for (int i = 0; i < 4; ++i) {
                float a = As[k][ty * 4 + i];
                acc[i][0] = fmaf(a, b4.x, acc[i][0]);
                acc[i][1] = fmaf(a, b4.y, acc[i][1]);
                acc[i][2] = fmaf(a, b4.z, acc[i][2]);
                acc[i][3] = fmaf(a, b4.w, acc[i][3]);
            }
        }
        __syncthreads();
    }

    #pragma unroll
    for (int i = 0; i < 4; ++i) {
        int mrow = m0 + ty * 4 + i;
        if (mrow < M) {
            int n = n0 + tx * 4;
            float4 o;
            o.x = (acc[i][0] + bias[n + 0]) * alpha;
            o.y = (acc[i][1] + bias[n + 1]) * alpha;
            o.z = (acc[i][2] + bias[n + 2]) * alpha;
            o.w = (acc[i][3] + bias[n + 3]) * alpha;
            *(float4*)(Y + (size_t)mrow * 256 + n) = o;
        }
    }
}

// ---------------------------------------------------------------------------
// RPE MLP: one thread per (b, q, pos). Computes both the x-axis and y-axis
// MLP (2 -> 512 relu -> 8). Outputs rpe_x/rpe_y laid out [b][q][pos][h].
// ---------------------------------------------------------------------------
__global__ __launch_bounds__(256) void rpe_kernel(
    const float* __restrict__ ref2d,
    const float* __restrict__ W1x, const float* __restrict__ b1x, const float* __restrict__ W2x,
    const float* __restrict__ W1y, const float* __restrict__ b1y, const float* __restrict__ W2y,
    float* __restrict__ rpe_x, float* __restrict__ rpe_y)
{
    __shared__ float sW1x[1024], sb1x[512], sW2x[4096];
    __shared__ float sW1y[1024], sb1y[512], sW2y[4096];
    const int tid = threadIdx.x;
    for (int i = tid; i < 1024; i += 256) { sW1x[i] = W1x[i]; sW1y[i] = W1y[i]; }
    for (int i = tid; i < 512;  i += 256) { sb1x[i] = b1x[i]; sb1y[i] = b1y[i]; }
    for (int i = tid; i < 4096; i += 256) { sW2x[i] = W2x[i]; sW2y[i] = W2y[i]; }
    __syncthreads();

    const int gid = blockIdx.x * 256 + tid;       // < B*NQ*64 = 115200 exactly
    const int pos = gid & 63;
    const int bq  = gid >> 6;                      // b*900+q
    const float4 r = *(const float4*)(ref2d + (size_t)bq * 4);  // cx, cy, w, h
    const float pc = (pos + 0.5f) * 16.0f;
    const float dx0 = (r.x - r.z * 0.5f) - pc;
    const float dx1 = (r.x + r.z * 0.5f) - pc;
    const float dy0 = (r.y - r.w * 0.5f) - pc;
    const float dy1 = (r.y + r.w * 0.5f) - pc;

    float ax[8] = {}, ay[8] = {};
    for (int j = 0; j < 512; ++j) {
        float hx = fmaf(dx0, sW1x[j], fmaf(dx1, sW1x[512 + j], sb1x[j]));
        float hy = fmaf(dy0, sW1y[j], fmaf(dy1, sW1y[512 + j], sb1y[j]));
        hx = fmaxf(hx, 0.f);
        hy = fmaxf(hy, 0.f);
        #pragma unroll
        for (int t = 0; t < 8; ++t) {
            ax[t] = fmaf(hx, sW2x[j * 8 + t], ax[t]);
            ay[t] = fmaf(hy, sW2y[j * 8 + t], ay[t]);
        }
    }
    #pragma unroll
    for (int t = 0; t < 8; ++t) {
        rpe_x[(size_t)gid * 8 + t] = ax[t];
        rpe_y[(size_t)gid * 8 + t] = ay[t];
    }
}

// ---------------------------------------------------------------------------
// Fused attention, 1024-thread blocks (16 waves/CU -> ~50% occupancy with one
// block/CU). Block = (query-tile 64, head, b). Threads = 64 q x 16 key-slices
// (4 keys each per 64-key chunk). Each thread keeps an online-softmax partial
// (m, l, acc[32]); the 16 slice-partials per query merge through LDS at the
// end. k/v chunk c+1 is prefetched into registers during compute of chunk c,
// so the global-load latency is off the barrier's critical path.
// Chunk c == feature-map row c, so rpe_y enters as a per-(q,chunk) scalar.
// ---------------------------------------------------------------------------
__global__ __launch_bounds__(1024, 4) void attn_kernel(
    const float* __restrict__ q, const float* __restrict__ k, const float* __restrict__ v,
    const float* __restrict__ rpe_x, const float* __restrict__ rpe_y,
    const unsigned char* __restrict__ mask, float* __restrict__ xout)
{
    __shared__ float kv[4096];          // k chunk [64][32] @0, v @2048; reused as ot[64][33]
    __shared__ float rx[64 * 65];       // [q][col], stride 65 (2-way max -> free)
    __shared__ float ry[64 * 65];       // [q][row], stride 65
    __shared__ float sm[16][64], sl[16][64], smsk[64];

    const int tid = threadIdx.x;
    const int qb = blockIdx.x, h = blockIdx.y, b = blockIdx.z;
    const int q0 = qb * 64;
    const int qi = tid & 63, slice = tid >> 6;    // slice = wave id

    // q fragment in registers
    float4 qv[8];
    {
        int qq = q0 + qi;
        if (qq < NQ_) {
            const float* qp = q + ((size_t)(b * NQ_ + qq) * 256 + h * 32);
            #pragma unroll
            for (int d = 0; d < 8; ++d) qv[d] = *(const float4*)(qp + d * 4);
        } else {
            #pragma unroll
            for (int d = 0; d < 8; ++d) qv[d] = make_float4(0.f, 0.f, 0.f, 0.f);
        }
    }
    // rpe tiles [64 q][64 pos]
    for (int i = tid; i < 4096; i += 1024) {
        int qq = q0 + (i >> 6), pos = i & 63;
        float vx = 0.f, vy = 0.f;
        if (qq < NQ_) {
            size_t base = ((size_t)(b * NQ_ + qq) * 64 + pos) * 8 + h;
            vx = rpe_x[base];
            vy = rpe_y[base];
        }
        rx[(i >> 6) * 65 + pos] = vx;
        ry[(i >> 6) * 65 + pos] = vy;
    }

    // staging role: tid<512 loads k, else v; one float4 per thread per chunk
    const int si  = tid & 511;
    const int key = si >> 3, d4 = si & 7;
    const float* kvsrc = (tid < 512) ? k : v;
    const int ldsoff = ((tid < 512) ? 0 : 2048) + key * 32 + d4 * 4;
    const size_t gbase = ((size_t)(b * N_) + key) * 256 + h * 32 + d4 * 4;

    float4 pf = *(const float4*)(kvsrc + gbase);          // prefetch chunk 0
    float pmsk = 0.f;
    if (tid < 64) pmsk = mask[(size_t)b * N_ + tid] ? -100.0f : 0.0f;

    float m = -INFINITY, l = 0.f;
    float4 acc[8];
    #pragma unroll
    for (int d = 0; d < 8; ++d) acc[d] = make_float4(0.f, 0.f, 0.f, 0.f);

    for (int c = 0; c < 64; ++c) {
        __syncthreads();                 // prev chunk fully consumed (covers rx/ry on c=0)
        *(float4*)(&kv[ldsoff]) = pf;
        if (tid < 64) smsk[tid] = pmsk;
        __syncthreads();

        // prefetch chunk c+1 (clamped; redundant reload on last iter is harmless)
        {
            int cn = (c + 1 < 64) ? c + 1 : 63;
            pf = *(const float4*)(kvsrc + gbase + (size_t)cn * 64 * 256);
            if (tid < 64) pmsk = mask[(size_t)b * N_ + cn * 64 + tid] ? -100.0f : 0.0f;
        }

        const float ryv = ry[qi * 65 + c];
        float sc[4];
        float cmax = -INFINITY;
        #pragma unroll
        for (int j = 0; j < 4; ++j) {
            int kk = slice * 4 + j;                       // wave-uniform -> broadcast
            const float4* kp = (const float4*)(&kv[kk * 32]);
            float s = 0.f;
            #pragma unroll
            for (int d = 0; d < 8; ++d) {
                float4 kd = kp[d];
                s = fmaf(qv[d].x, kd.x, s);
                s = fmaf(qv[d].y, kd.y, s);
                s = fmaf(qv[d].z, kd.z, s);
                s = fmaf(qv[d].w, kd.w, s);
            }
            s += rx[qi * 65 + kk] + ryv + smsk[kk];
            sc[j] = s;
            cmax = fmaxf(cmax, s);
        }
        float mnew = fmaxf(m, cmax);
        float alpha = __expf(m - mnew);   // first chunk: exp(-inf)=0, safe
        l *= alpha;
        #pragma unroll
        for (int d = 0; d < 8; ++d) {
            acc[d].x *= alpha; acc[d].y *= alpha; acc[d].z *= alpha; acc[d].w *= alpha;
        }
        #pragma unroll
        for (int j = 0; j < 4; ++j) {
            int kk = slice * 4 + j;
            float p = __expf(sc[j] - mnew);
            l += p;
            const float4* vp = (const float4*)(&kv[2048 + kk * 32]);
            #pragma unroll
            for (int d = 0; d < 8; ++d) {
                float4 vd = vp[d];
                acc[d].x = fmaf(p, vd.x, acc[d].x);
                acc[d].y = fmaf(p, vd.y, acc[d].y);
                acc[d].z = fmaf(p, vd.z, acc[d].z);
                acc[d].w = fmaf(p, vd.w, acc[d].w);
            }
        }
        m = mnew;
    }

    __syncthreads();                     // all kv reads done before sm/sl + ot reuse
    sm[slice][qi] = m;
    sl[slice][qi] = l;
    __syncthreads();

    float mg = -INFINITY;
    #pragma unroll
    for (int s = 0; s < 16; ++s) mg = fmaxf(mg, sm[s][qi]);
    float lg = 0.f;
    #pragma unroll
    for (int s = 0; s < 16; ++s) lg = fmaf(__expf(sm[s][qi] - mg), sl[s][qi], lg);
    const float wgt = __expf(m - mg) / lg;

    // serialized slice merge into ot[64][33] (each pass is exactly one wave)
    float* ot = kv;
    for (int s = 0; s < 16; ++s) {
        if (slice == s) {
            #pragma unroll
            for (int d = 0; d < 8; ++d) {
                int base = qi * 33 + d * 4;
                if (s == 0) {
                    ot[base + 0] = wgt * acc[d].x;
                    ot[base + 1] = wgt * acc[d].y;
                    ot[base + 2] = wgt * acc[d].z;
                    ot[base + 3] = wgt * acc[d].w;
                } else {
                    ot[base + 0] += wgt * acc[d].x;
                    ot[base + 1] += wgt * acc[d].y;
                    ot[base + 2] += wgt * acc[d].z;
                    ot[base + 3] += wgt * acc[d].w;
                }
            }
        }
        __syncthreads();
    }

    for (int i = tid; i < 2048; i += 1024) {
        int qi2 = i >> 5, d = i & 31;
        int qq = q0 + qi2;
        if (qq < NQ_)
            xout[(size_t)(b * NQ_ + qq) * 256 + h * 32 + d] = ot[qi2 * 33 + d];
    }
}

// ---------------------------------------------------------------------------
extern "C" void kernel_launch(void* const* d_in, const int* in_sizes, int n_in,
                              void* d_out, int out_size, void* d_ws, size_t ws_size,
                              hipStream_t stream)
{
    const float* query = (const float*)d_in[1];
    const float* ref2d = (const float*)d_in[2];
    const float* kin   = (const float*)d_in[3];
    const float* vin   = (const float*)d_in[4];
    const unsigned char* mask = (const unsigned char*)d_in[6];
    const float* W1x = (const float*)d_in[7];
    const float* b1x = (const float*)d_in[8];
    const float* W2x = (const float*)d_in[9];
    const float* W1y = (const float*)d_in[10];
    const float* b1y = (const float*)d_in[11];
    const float* W2y = (const float*)d_in[12];
    const float* Wq  = (const float*)d_in[13];
    const float* bq  = (const float*)d_in[14];
    const float* Wk  = (const float*)d_in[15];
    const float* bk  = (const float*)d_in[16];
    const float* Wv  = (const float*)d_in[17];
    const float* bv  = (const float*)d_in[18];
    const float* Wp  = (const float*)d_in[19];
    const float* bp  = (const float*)d_in[20];

    // Workspace layout: 6,959,104 floats = 27.8 MB (round-1-proven footprint;
    // round 2's 61 MB overflowed ws_size and corrupted adjacent buffers).
    float* ws   = (float*)d_ws;
    float* qws  = ws;                          // 1800*256   = 460800
    float* kws  = qws + 460800;                // 8192*256   = 2097152
    float* vws  = kws + 2097152;               // 8192*256   = 2097152
    float* rxws = vws + 2097152;               // 2*900*64*8 = 921600
    float* ryws = rxws + 921600;               // 921600
    float* xws  = ryws + 921600;               // 460800
    float* out  = (float*)d_out;

    const float scale = 1.0f / sqrtf(32.0f);

    gemm_bias_kernel<<<dim3(29, 4),  256, 0, stream>>>(query, Wq, bq, qws, 1800, scale);
    gemm_bias_kernel<<<dim3(128, 4), 256, 0, stream>>>(kin,   Wk, bk, kws, 8192, 1.0f);
    gemm_bias_kernel<<<dim3(128, 4), 256, 0, stream>>>(vin,   Wv, bv, vws, 8192, 1.0f);
    rpe_kernel<<<450, 256, 0, stream>>>(ref2d, W1x, b1x, W2x, W1y, b1y, W2y, rxws, ryws);
    attn_kernel<<<dim3(15, 8, B_), 1024, 0, stream>>>(qws, kws, vws, rxws, ryws, mask, xws);
    gemm_bias_kernel<<<dim3(29, 4),  256, 0, stream>>>(xws, Wp, bp, out, 1800, 1.0f);
}

// Round 4
// 299.812 us; speedup vs baseline: 2.3070x; 1.3185x over previous
//
#include <hip/hip_runtime.h>
#include <hip/hip_bf16.h>
#include <cmath>

// Problem constants
#define B_ 2
#define NQ_ 900
#define C_ 256
#define H_ 8
#define N_ 4096
#define DH_ 32

typedef __attribute__((ext_vector_type(4))) float f32x4;
typedef __attribute__((ext_vector_type(8))) short s16x8;

__device__ inline short f2bf(float x) {
    union { __hip_bfloat16 b; short s; } u;
    u.b = __float2bfloat16(x);
    return u.s;
}

// ---------------------------------------------------------------------------
// fp32 GEMM: Y[M,256] = (X[M,256] @ W[256,256] + bias) * alpha  (fp32 out)
// ---------------------------------------------------------------------------
__global__ __launch_bounds__(256) void gemm_bias_kernel(
    const float* __restrict__ X, const float* __restrict__ W,
    const float* __restrict__ bias, float* __restrict__ Y,
    int M, float alpha)
{
    __shared__ float As[16][65];
    __shared__ float Bs[16][64];
    const int tid = threadIdx.x;
    const int tx = tid & 15, ty = tid >> 4;
    const int m0 = blockIdx.x * 64;
    const int n0 = blockIdx.y * 64;
    const int arow = tid >> 2, acol4 = tid & 3;
    const int brow = tid >> 4, bcol4 = tid & 15;

    float acc[4][4] = {};
    for (int k0 = 0; k0 < 256; k0 += 16) {
        float4 av = make_float4(0.f, 0.f, 0.f, 0.f);
        if (m0 + arow < M)
            av = *(const float4*)(X + (size_t)(m0 + arow) * 256 + k0 + acol4 * 4);
        As[acol4 * 4 + 0][arow] = av.x;
        As[acol4 * 4 + 1][arow] = av.y;
        As[acol4 * 4 + 2][arow] = av.z;
        As[acol4 * 4 + 3][arow] = av.w;
        float4 bv = *(const float4*)(W + (size_t)(k0 + brow) * 256 + n0 + bcol4 * 4);
        *(float4*)(&Bs[brow][bcol4 * 4]) = bv;
        __syncthreads();
        #pragma unroll
        for (int k = 0; k < 16; ++k) {
            float4 b4 = *(const float4*)(&Bs[k][tx * 4]);
            #pragma unroll
            for (int i = 0; i < 4; ++i) {
                float a = As[k][ty * 4 + i];
                acc[i][0] = fmaf(a, b4.x, acc[i][0]);
                acc[i][1] = fmaf(a, b4.y, acc[i][1]);
                acc[i][2] = fmaf(a, b4.z, acc[i][2]);
                acc[i][3] = fmaf(a, b4.w, acc[i][3]);
            }
        }
        __syncthreads();
    }
    #pragma unroll
    for (int i = 0; i < 4; ++i) {
        int mrow = m0 + ty * 4 + i;
        if (mrow < M) {
            int n = n0 + tx * 4;
            float4 o;
            o.x = (acc[i][0] + bias[n + 0]) * alpha;
            o.y = (acc[i][1] + bias[n + 1]) * alpha;
            o.z = (acc[i][2] + bias[n + 2]) * alpha;
            o.w = (acc[i][3] + bias[n + 3]) * alpha;
            *(float4*)(Y + (size_t)mrow * 256 + n) = o;
        }
    }
}

// ---------------------------------------------------------------------------
// Same GEMM, but epilogue writes bf16 in [b][h][pos][32] layout for MFMA attn.
// row r -> (b = r/rows_per_b, pos = r%rows_per_b); col n -> (h = n>>5, d = n&31)
// ---------------------------------------------------------------------------
__global__ __launch_bounds__(256) void gemm_bias_bf16h_kernel(
    const float* __restrict__ X, const float* __restrict__ W,
    const float* __restrict__ bias, unsigned short* __restrict__ Y,
    int M, float alpha, int rows_per_b, int ROWS)
{
    __shared__ float As[16][65];
    __shared__ float Bs[16][64];
    const int tid = threadIdx.x;
    const int tx = tid & 15, ty = tid >> 4;
    const int m0 = blockIdx.x * 64;
    const int n0 = blockIdx.y * 64;
    const int arow = tid >> 2, acol4 = tid & 3;
    const int brow = tid >> 4, bcol4 = tid & 15;

    float acc[4][4] = {};
    for (int k0 = 0; k0 < 256; k0 += 16) {
        float4 av = make_float4(0.f, 0.f, 0.f, 0.f);
        if (m0 + arow < M)
            av = *(const float4*)(X + (size_t)(m0 + arow) * 256 + k0 + acol4 * 4);
        As[acol4 * 4 + 0][arow] = av.x;
        As[acol4 * 4 + 1][arow] = av.y;
        As[acol4 * 4 + 2][arow] = av.z;
        As[acol4 * 4 + 3][arow] = av.w;
        float4 bv = *(const float4*)(W + (size_t)(k0 + brow) * 256 + n0 + bcol4 * 4);
        *(float4*)(&Bs[brow][bcol4 * 4]) = bv;
        __syncthreads();
        #pragma unroll
        for (int k = 0; k < 16; ++k) {
            float4 b4 = *(const float4*)(&Bs[k][tx * 4]);
            #pragma unroll
            for (int i = 0; i < 4; ++i) {
                float a = As[k][ty * 4 + i];
                acc[i][0] = fmaf(a, b4.x, acc[i][0]);
                acc[i][1] = fmaf(a, b4.y, acc[i][1]);
                acc[i][2] = fmaf(a, b4.z, acc[i][2]);
                acc[i][3] = fmaf(a, b4.w, acc[i][3]);
            }
        }
        __syncthreads();
    }
    #pragma unroll
    for (int i = 0; i < 4; ++i) {
        int r = m0 + ty * 4 + i;
        if (r < M) {
            int n = n0 + tx * 4;
            int b = r / rows_per_b;
            int pos = r - b * rows_per_b;
            int h = n >> 5, d = n & 31;
            ushort4 o;
            o.x = (unsigned short)f2bf((acc[i][0] + bias[n + 0]) * alpha);
            o.y = (unsigned short)f2bf((acc[i][1] + bias[n + 1]) * alpha);
            o.z = (unsigned short)f2bf((acc[i][2] + bias[n + 2]) * alpha);
            o.w = (unsigned short)f2bf((acc[i][3] + bias[n + 3]) * alpha);
            *(ushort4*)(Y + (((size_t)(b * 8 + h) * ROWS + pos) * 32 + d)) = o;
        }
    }
}

// ---------------------------------------------------------------------------
// RPE MLP (unchanged): outputs rpe_x/rpe_y [b][q][pos][h] fp32
// ---------------------------------------------------------------------------
__global__ __launch_bounds__(256) void rpe_kernel(
    const float* __restrict__ ref2d,
    const float* __restrict__ W1x, const float* __restrict__ b1x, const float* __restrict__ W2x,
    const float* __restrict__ W1y, const float* __restrict__ b1y, const float* __restrict__ W2y,
    float* __restrict__ rpe_x, float* __restrict__ rpe_y)
{
    __shared__ float sW1x[1024], sb1x[512], sW2x[4096];
    __shared__ float sW1y[1024], sb1y[512], sW2y[4096];
    const int tid = threadIdx.x;
    for (int i = tid; i < 1024; i += 256) { sW1x[i] = W1x[i]; sW1y[i] = W1y[i]; }
    for (int i = tid; i < 512;  i += 256) { sb1x[i] = b1x[i]; sb1y[i] = b1y[i]; }
    for (int i = tid; i < 4096; i += 256) { sW2x[i] = W2x[i]; sW2y[i] = W2y[i]; }
    __syncthreads();

    const int gid = blockIdx.x * 256 + tid;
    const int pos = gid & 63;
    const int bq  = gid >> 6;
    const float4 r = *(const float4*)(ref2d + (size_t)bq * 4);
    const float pc = (pos + 0.5f) * 16.0f;
    const float dx0 = (r.x - r.z * 0.5f) - pc;
    const float dx1 = (r.x + r.z * 0.5f) - pc;
    const float dy0 = (r.y - r.w * 0.5f) - pc;
    const float dy1 = (r.y + r.w * 0.5f) - pc;

    float ax[8] = {}, ay[8] = {};
    for (int j = 0; j < 512; ++j) {
        float hx = fmaf(dx0, sW1x[j], fmaf(dx1, sW1x[512 + j], sb1x[j]));
        float hy = fmaf(dy0, sW1y[j], fmaf(dy1, sW1y[512 + j], sb1y[j]));
        hx = fmaxf(hx, 0.f);
        hy = fmaxf(hy, 0.f);
        #pragma unroll
        for (int t = 0; t < 8; ++t) {
            ax[t] = fmaf(hx, sW2x[j * 8 + t], ax[t]);
            ay[t] = fmaf(hy, sW2y[j * 8 + t], ay[t]);
        }
    }
    #pragma unroll
    for (int t = 0; t < 8; ++t) {
        rpe_x[(size_t)gid * 8 + t] = ax[t];
        rpe_y[(size_t)gid * 8 + t] = ay[t];
    }
}

// ---------------------------------------------------------------------------
// MFMA flash attention. Block = (q-tile 64, head, batch), 1024 threads =
// 16 waves = 4 q-subtiles x 4 key-splits. Each iteration stages 4 chunks
// (64 keys each, one per ksplit) in frag-friendly LDS layouts; each wave does
// QK (4 MFMAs) -> fp32 online softmax (C-layout: row=quad*4+reg, col=lane&15)
// -> P bf16 via wave-private LDS round-trip into A-layout -> PV (4 MFMAs).
// rpe_x is hoisted into 16 registers (chunk-invariant); rpe_y is one scalar
// per (q,row). Final: 4 ksplit partials merged via LDS.
// ---------------------------------------------------------------------------
__global__ __launch_bounds__(1024) void attn_mfma_kernel(
    const unsigned short* __restrict__ qb16, const unsigned short* __restrict__ kb16,
    const unsigned short* __restrict__ vb16,
    const float* __restrict__ rpe_x, const float* __restrict__ rpe_y,
    const unsigned char* __restrict__ mask, float* __restrict__ xout)
{
    __shared__ short skf[4 * 2048];      // K frags, per ksplit: slot (kt*4+quad)*16+k15, 8 bf16
    __shared__ short svt[4 * 2304];      // V^T,   per ksplit: [32 d][72 stride] bf16
    __shared__ short spb[16 * 544];      // P buf, per wave: [4 groups x17 + q][8 bf16]
    __shared__ float rx[64 * 65];        // [q][col] fp32
    __shared__ float ry[64 * 65];        // [q][row] fp32
    __shared__ float sm[16][16], sl[16][16], sLf[64];

    const int tid = threadIdx.x;
    const int qb = blockIdx.x, h = blockIdx.y, b = blockIdx.z;
    const int q0 = qb * 64;
    const int w = tid >> 6, l = tid & 63;
    const int qsub = w >> 2, g = w & 3;          // w = qsub*4 + g
    const int quad = l >> 4, l15 = l & 15;

    const unsigned short* qg = qb16 + (size_t)(b * 8 + h) * 960 * 32;
    const unsigned short* kg = kb16 + (size_t)(b * 8 + h) * 4096 * 32;
    const unsigned short* vg = vb16 + (size_t)(b * 8 + h) * 4096 * 32;

    // rpe tiles
    for (int i = tid; i < 4096; i += 1024) {
        int qq = q0 + (i >> 6), pos = i & 63;
        float vx = 0.f, vy = 0.f;
        if (qq < NQ_) {
            size_t base = ((size_t)(b * NQ_ + qq) * 64 + pos) * 8 + h;
            vx = rpe_x[base];
            vy = rpe_y[base];
        }
        rx[(i >> 6) * 65 + pos] = vx;
        ry[(i >> 6) * 65 + pos] = vy;
    }

    // Q A-fragment: lane holds Q[q0+qsub*16+l15][quad*8 .. +8]
    s16x8 qa = *(const s16x8*)(qg + (size_t)(q0 + qsub * 16 + l15) * 32 + quad * 8);

    // staging roles: threads sg*256.. stage ksplit sg's chunk
    const int sg  = tid >> 8;
    const int st  = tid & 255;
    const int wsl = st >> 6, stl = st & 63;
    const int keyK = wsl * 16 + (stl & 15), qdK = stl >> 4;  // K: frag-order slot = wsl*64+stl
    const int keyV = stl, dgV = wsl;                          // V: wave wsl stages d-rows dgV*8..+8

    uint4 kpf = *(const uint4*)(kg + ((size_t)(sg * 16) * 64 + keyK) * 32 + qdK * 8);
    uint4 vpf = *(const uint4*)(vg + ((size_t)(sg * 16) * 64 + keyV) * 32 + dgV * 8);

    __syncthreads();   // rx/ry visible
    // hoist rpe_x fragment (chunk-invariant): rxr[tile][reg]
    float rxr[4][4];
    #pragma unroll
    for (int t = 0; t < 4; ++t)
        #pragma unroll
        for (int r = 0; r < 4; ++r)
            rxr[t][r] = rx[(qsub * 16 + quad * 4 + r) * 65 + t * 16 + l15];

    float mrow[4] = {-INFINITY, -INFINITY, -INFINITY, -INFINITY};
    float lrow[4] = {0.f, 0.f, 0.f, 0.f};
    f32x4 acc0 = {0.f, 0.f, 0.f, 0.f}, acc1 = {0.f, 0.f, 0.f, 0.f};
    short* pw = spb + w * 544;

    for (int i = 0; i < 16; ++i) {
        __syncthreads();                                  // prev chunks consumed
        *(uint4*)(skf + sg * 2048 + (wsl * 64 + stl) * 8) = kpf;
        {
            const unsigned short* pv = (const unsigned short*)&vpf;
            short* vtw = svt + sg * 2304;
            #pragma unroll
            for (int j = 0; j < 8; ++j)
                vtw[(dgV * 8 + j) * 72 + keyV] = (short)pv[j];
        }
        __syncthreads();

        // prefetch next iteration's chunk
        {
            int inext = (i + 1 < 16) ? i + 1 : 15;
            size_t cgn = (size_t)(sg * 16 + inext) * 64;
            kpf = *(const uint4*)(kg + (cgn + keyK) * 32 + qdK * 8);
            vpf = *(const uint4*)(vg + (cgn + keyV) * 32 + dgV * 8);
        }

        const int cgc = g * 16 + i;                       // chunk == feature row
        const short* kf = skf + g * 2048;

        // QK^T: 4 MFMAs -> 16 scores/lane (C layout)
        f32x4 sc[4];
        #pragma unroll
        for (int t = 0; t < 4; ++t) {
            s16x8 kb = *(const s16x8*)(kf + (t * 64 + l) * 8);
            f32x4 z = {0.f, 0.f, 0.f, 0.f};
            sc[t] = __builtin_amdgcn_mfma_f32_16x16x32_bf16(qa, kb, z, 0, 0, 0);
        }
        // bias: rpe_x + rpe_y + mask
        float ryv[4];
        #pragma unroll
        for (int r = 0; r < 4; ++r)
            ryv[r] = ry[(qsub * 16 + quad * 4 + r) * 65 + cgc];
        #pragma unroll
        for (int t = 0; t < 4; ++t) {
            float mk = mask[(size_t)b * N_ + cgc * 64 + t * 16 + l15] ? -100.f : 0.f;
            #pragma unroll
            for (int r = 0; r < 4; ++r)
                sc[t][r] += rxr[t][r] + ryv[r] + mk;
        }
        // row max (across 16 col-lanes)
        float cm[4];
        #pragma unroll
        for (int r = 0; r < 4; ++r)
            cm[r] = fmaxf(fmaxf(sc[0][r], sc[1][r]), fmaxf(sc[2][r], sc[3][r]));
        #pragma unroll
        for (int off = 1; off < 16; off <<= 1)
            #pragma unroll
            for (int r = 0; r < 4; ++r)
                cm[r] = fmaxf(cm[r], __shfl_xor(cm[r], off, 16));
        // online-softmax update
        float al[4];
        #pragma unroll
        for (int r = 0; r < 4; ++r) {
            float mnew = fmaxf(mrow[r], cm[r]);
            al[r] = __expf(mrow[r] - mnew);
            mrow[r] = mnew;
            lrow[r] *= al[r];
            acc0[r] *= al[r];
            acc1[r] *= al[r];
        }
        #pragma unroll
        for (int t = 0; t < 4; ++t)
            #pragma unroll
            for (int r = 0; r < 4; ++r)
                sc[t][r] = __expf(sc[t][r] - mrow[r]);
        float rs[4];
        #pragma unroll
        for (int r = 0; r < 4; ++r)
            rs[r] = (sc[0][r] + sc[1][r]) + (sc[2][r] + sc[3][r]);
        #pragma unroll
        for (int off = 1; off < 16; off <<= 1)
            #pragma unroll
            for (int r = 0; r < 4; ++r)
                rs[r] += __shfl_xor(rs[r], off, 16);
        #pragma unroll
        for (int r = 0; r < 4; ++r)
            lrow[r] += rs[r];

        // PV per 32-key half: P -> LDS (A-layout) -> MFMA with V^T frags
        const short* vt = svt + g * 2304;
        #pragma unroll
        for (int hh = 0; hh < 2; ++hh) {
            #pragma unroll
            for (int tt = 0; tt < 2; ++tt) {
                int t = hh * 2 + tt;
                #pragma unroll
                for (int r = 0; r < 4; ++r)
                    pw[((tt * 2 + (l15 >> 3)) * 17 + quad * 4 + r) * 8 + (l15 & 7)] =
                        f2bf(sc[t][r]);
            }
            s16x8 pa  = *(const s16x8*)(pw + (quad * 17 + l15) * 8);
            s16x8 vb0 = *(const s16x8*)(vt + (l15)      * 72 + hh * 32 + quad * 8);
            s16x8 vb1 = *(const s16x8*)(vt + (16 + l15) * 72 + hh * 32 + quad * 8);
            acc0 = __builtin_amdgcn_mfma_f32_16x16x32_bf16(pa, vb0, acc0, 0, 0, 0);
            acc1 = __builtin_amdgcn_mfma_f32_16x16x32_bf16(pa, vb1, acc1, 0, 0, 0);
        }
    }

    // ---- merge 4 ksplit partials per q ----
    __syncthreads();
    if (l15 == 0) {
        #pragma unroll
        for (int r = 0; r < 4; ++r) {
            sm[w][quad * 4 + r] = mrow[r];
            sl[w][quad * 4 + r] = lrow[r];
        }
    }
    __syncthreads();
    float wgt[4], L4[4];
    #pragma unroll
    for (int r = 0; r < 4; ++r) {
        int qrow = quad * 4 + r;
        float mm = -INFINITY;
        #pragma unroll
        for (int gg = 0; gg < 4; ++gg) mm = fmaxf(mm, sm[qsub * 4 + gg][qrow]);
        float LL = 0.f;
        #pragma unroll
        for (int gg = 0; gg < 4; ++gg)
            LL += __expf(sm[qsub * 4 + gg][qrow] - mm) * sl[qsub * 4 + gg][qrow];
        wgt[r] = __expf(mrow[r] - mm);
        L4[r] = LL;
    }
    if (g == 0 && l15 == 0) {
        #pragma unroll
        for (int r = 0; r < 4; ++r) sLf[qsub * 16 + quad * 4 + r] = L4[r];
    }

    float* obuf = (float*)skf;    // 64x33 fp32 = 8.4 KB, fits in skf (16 KB)
    for (int gg = 0; gg < 4; ++gg) {
        if (g == gg) {
            #pragma unroll
            for (int r = 0; r < 4; ++r) {
                int idx = (qsub * 16 + quad * 4 + r) * 33 + l15;
                float v0 = wgt[r] * acc0[r];
                float v1 = wgt[r] * acc1[r];
                if (gg == 0) { obuf[idx] = v0; obuf[idx + 16] = v1; }
                else         { obuf[idx] += v0; obuf[idx + 16] += v1; }
            }
        }
        __syncthreads();
    }

    for (int i = tid; i < 2048; i += 1024) {
        int ql = i >> 5, d = i & 31;
        int qq = q0 + ql;
        if (qq < NQ_)
            xout[(size_t)(b * NQ_ + qq) * 256 + h * 32 + d] = obuf[ql * 33 + d] / sLf[ql];
    }
}

// ---------------------------------------------------------------------------
extern "C" void kernel_launch(void* const* d_in, const int* in_sizes, int n_in,
                              void* d_out, int out_size, void* d_ws, size_t ws_size,
                              hipStream_t stream)
{
    const float* query = (const float*)d_in[1];
    const float* ref2d = (const float*)d_in[2];
    const float* kin   = (const float*)d_in[3];
    const float* vin   = (const float*)d_in[4];
    const unsigned char* mask = (const unsigned char*)d_in[6];
    const float* W1x = (const float*)d_in[7];
    const float* b1x = (const float*)d_in[8];
    const float* W2x = (const float*)d_in[9];
    const float* W1y = (const float*)d_in[10];
    const float* b1y = (const float*)d_in[11];
    const float* W2y = (const float*)d_in[12];
    const float* Wq  = (const float*)d_in[13];
    const float* bq  = (const float*)d_in[14];
    const float* Wk  = (const float*)d_in[15];
    const float* bk  = (const float*)d_in[16];
    const float* Wv  = (const float*)d_in[17];
    const float* bv  = (const float*)d_in[18];
    const float* Wp  = (const float*)d_in[19];
    const float* bp  = (const float*)d_in[20];

    // Workspace (18.6 MB total, well under the proven 27.8 MB footprint):
    char* wsb = (char*)d_ws;
    unsigned short* qbf = (unsigned short*)wsb;                       // 2*8*960*32 bf16  = 983040 B
    unsigned short* kbf = (unsigned short*)(wsb + 983040);            // 2*8*4096*32 bf16 = 4194304 B
    unsigned short* vbf = (unsigned short*)(wsb + 983040 + 4194304);  // 4194304 B
    float* rxws = (float*)(wsb + 983040 + 2 * 4194304);               // 921600 f32
    float* ryws = rxws + 921600;                                      // 921600 f32
    float* xws  = ryws + 921600;                                      // 460800 f32
    float* out  = (float*)d_out;

    const float scale = 1.0f / sqrtf(32.0f);

    gemm_bias_bf16h_kernel<<<dim3(29, 4),  256, 0, stream>>>(query, Wq, bq, qbf, 1800, scale, 900, 960);
    gemm_bias_bf16h_kernel<<<dim3(128, 4), 256, 0, stream>>>(kin,   Wk, bk, kbf, 8192, 1.0f, 4096, 4096);
    gemm_bias_bf16h_kernel<<<dim3(128, 4), 256, 0, stream>>>(vin,   Wv, bv, vbf, 8192, 1.0f, 4096, 4096);
    rpe_kernel<<<450, 256, 0, stream>>>(ref2d, W1x, b1x, W2x, W1y, b1y, W2y, rxws, ryws);
    attn_mfma_kernel<<<dim3(15, 8, B_), 1024, 0, stream>>>(qbf, kbf, vbf, rxws, ryws, mask, xws);
    gemm_bias_kernel<<<dim3(29, 4),  256, 0, stream>>>(xws, Wp, bp, out, 1800, 1.0f);
}

// Round 5
// 261.377 us; speedup vs baseline: 2.6462x; 1.1470x over previous
//
#include <hip/hip_runtime.h>
#include <hip/hip_bf16.h>
#include <cmath>

// Problem constants
#define B_ 2
#define NQ_ 900
#define C_ 256
#define H_ 8
#define N_ 4096
#define DH_ 32

typedef __attribute__((ext_vector_type(4))) float f32x4;
typedef __attribute__((ext_vector_type(8))) short s16x8;

__device__ inline short f2bf(float x) {
    union { __hip_bfloat16 b; short s; } u;
    u.b = __float2bfloat16(x);
    return u.s;
}

// ---------------------------------------------------------------------------
// Transpose+convert Wq/Wk/Wv (fp32 [k][n]) -> WT bf16 [mtx][n][k]
// ---------------------------------------------------------------------------
__global__ __launch_bounds__(256) void wtconv_kernel(
    const float* __restrict__ Wq, const float* __restrict__ Wk,
    const float* __restrict__ Wv, unsigned short* __restrict__ wt)
{
    const float* W = (blockIdx.y == 0) ? Wq : (blockIdx.y == 1) ? Wk : Wv;
    int n = blockIdx.x, k = threadIdx.x;
    wt[(size_t)blockIdx.y * 65536 + n * 256 + k] = (unsigned short)f2bf(W[k * 256 + n]);
}

// ---------------------------------------------------------------------------
// MFMA bf16 GEMM: Y = (X[M,256] @ W[256,256] + bias) * alpha, output bf16 in
// [b][h][pos][32] layout. 64x64 tile, 256 thr (4 waves), K=256 fully LDS-
// resident (one barrier). A: fp32->bf16 convert in staging; B from WT bf16.
// LDS stores are lane-sequential 16B (conflict-free); frag reads are 256B
// runs per quad (conflict-free).
// ---------------------------------------------------------------------------
__global__ __launch_bounds__(256) void gemm_mfma_bf16h(
    const float* __restrict__ X, const unsigned short* __restrict__ WT,
    const float* __restrict__ bias, unsigned short* __restrict__ Y,
    int M, float alpha, int rows_per_b, int ROWS)
{
    __shared__ short Ab[32 * 64 * 8];   // [g2][m][j]  32 KB
    __shared__ short Bb[32 * 64 * 8];   // [g2][n][j]  32 KB
    const int tid = threadIdx.x;
    const int m0 = blockIdx.x * 64, n0 = blockIdx.y * 64;
    const int w = tid >> 6, l = tid & 63, quad = l >> 4, l15 = l & 15;

    {
        const int mm = tid & 63, wq = tid >> 6;
        const float* xr = X + (size_t)(m0 + mm) * 256;
        const bool valid = (m0 + mm) < M;
        const unsigned short* wr = WT + (size_t)(n0 + mm) * 256;
        #pragma unroll
        for (int it = 0; it < 8; ++it) {
            int g2 = it * 4 + wq;
            float4 a0 = make_float4(0.f, 0.f, 0.f, 0.f), a1 = a0;
            if (valid) {
                a0 = *(const float4*)(xr + g2 * 8);
                a1 = *(const float4*)(xr + g2 * 8 + 4);
            }
            ushort2 p0 = make_ushort2((unsigned short)f2bf(a0.x), (unsigned short)f2bf(a0.y));
            ushort2 p1 = make_ushort2((unsigned short)f2bf(a0.z), (unsigned short)f2bf(a0.w));
            ushort2 p2 = make_ushort2((unsigned short)f2bf(a1.x), (unsigned short)f2bf(a1.y));
            ushort2 p3 = make_ushort2((unsigned short)f2bf(a1.z), (unsigned short)f2bf(a1.w));
            uint4 pk;
            pk.x = (unsigned)p0.x | ((unsigned)p0.y << 16);
            pk.y = (unsigned)p1.x | ((unsigned)p1.y << 16);
            pk.z = (unsigned)p2.x | ((unsigned)p2.y << 16);
            pk.w = (unsigned)p3.x | ((unsigned)p3.y << 16);
            *(uint4*)(Ab + (g2 * 64 + mm) * 8) = pk;                   // lane-seq 16B
            *(uint4*)(Bb + (g2 * 64 + mm) * 8) = *(const uint4*)(wr + g2 * 8);
        }
    }
    __syncthreads();

    f32x4 acc[4] = {{0.f,0.f,0.f,0.f},{0.f,0.f,0.f,0.f},{0.f,0.f,0.f,0.f},{0.f,0.f,0.f,0.f}};
    #pragma unroll
    for (int kc = 0; kc < 8; ++kc) {
        s16x8 a = *(const s16x8*)(Ab + ((kc * 4 + quad) * 64 + w * 16 + l15) * 8);
        #pragma unroll
        for (int nt = 0; nt < 4; ++nt) {
            s16x8 bf = *(const s16x8*)(Bb + ((kc * 4 + quad) * 64 + nt * 16 + l15) * 8);
            acc[nt] = __builtin_amdgcn_mfma_f32_16x16x32_bf16(a, bf, acc[nt], 0, 0, 0);
        }
    }

    #pragma unroll
    for (int nt = 0; nt < 4; ++nt) {
        int n = n0 + nt * 16 + l15;
        float bs = bias[n];
        int h = n >> 5, d = n & 31;
        #pragma unroll
        for (int r = 0; r < 4; ++r) {
            int row = m0 + w * 16 + quad * 4 + r;
            if (row < M) {
                int b = row / rows_per_b;
                int pos = row - b * rows_per_b;
                Y[((size_t)(b * 8 + h) * ROWS + pos) * 32 + d] =
                    (unsigned short)f2bf((acc[nt][r] + bs) * alpha);
            }
        }
    }
}

// ---------------------------------------------------------------------------
// fp32 GEMM (kept for the output projection): Y = (X@W + bias) * alpha
// ---------------------------------------------------------------------------
__global__ __launch_bounds__(256) void gemm_bias_kernel(
    const float* __restrict__ X, const float* __restrict__ W,
    const float* __restrict__ bias, float* __restrict__ Y,
    int M, float alpha)
{
    __shared__ float As[16][65];
    __shared__ float Bs[16][64];
    const int tid = threadIdx.x;
    const int tx = tid & 15, ty = tid >> 4;
    const int m0 = blockIdx.x * 64;
    const int n0 = blockIdx.y * 64;
    const int arow = tid >> 2, acol4 = tid & 3;
    const int brow = tid >> 4, bcol4 = tid & 15;

    float acc[4][4] = {};
    for (int k0 = 0; k0 < 256; k0 += 16) {
        float4 av = make_float4(0.f, 0.f, 0.f, 0.f);
        if (m0 + arow < M)
            av = *(const float4*)(X + (size_t)(m0 + arow) * 256 + k0 + acol4 * 4);
        As[acol4 * 4 + 0][arow] = av.x;
        As[acol4 * 4 + 1][arow] = av.y;
        As[acol4 * 4 + 2][arow] = av.z;
        As[acol4 * 4 + 3][arow] = av.w;
        float4 bv = *(const float4*)(W + (size_t)(k0 + brow) * 256 + n0 + bcol4 * 4);
        *(float4*)(&Bs[brow][bcol4 * 4]) = bv;
        __syncthreads();
        #pragma unroll
        for (int k = 0; k < 16; ++k) {
            float4 b4 = *(const float4*)(&Bs[k][tx * 4]);
            #pragma unroll
            for (int i = 0; i < 4; ++i) {
                float a = As[k][ty * 4 + i];
                acc[i][0] = fmaf(a, b4.x, acc[i][0]);
                acc[i][1] = fmaf(a, b4.y, acc[i][1]);
                acc[i][2] = fmaf(a, b4.z, acc[i][2]);
                acc[i][3] = fmaf(a, b4.w, acc[i][3]);
            }
        }
        __syncthreads();
    }
    #pragma unroll
    for (int i = 0; i < 4; ++i) {
        int mrow = m0 + ty * 4 + i;
        if (mrow < M) {
            int n = n0 + tx * 4;
            float4 o;
            o.x = (acc[i][0] + bias[n + 0]) * alpha;
            o.y = (acc[i][1] + bias[n + 1]) * alpha;
            o.z = (acc[i][2] + bias[n + 2]) * alpha;
            o.w = (acc[i][3] + bias[n + 3]) * alpha;
            *(float4*)(Y + (size_t)mrow * 256 + n) = o;
        }
    }
}

// ---------------------------------------------------------------------------
// RPE MLP, vectorized LDS: W1/b1 interleaved (b128+b64), W2 via float4.
// ---------------------------------------------------------------------------
__global__ __launch_bounds__(256) void rpe_kernel(
    const float* __restrict__ ref2d,
    const float* __restrict__ W1x, const float* __restrict__ b1x, const float* __restrict__ W2x,
    const float* __restrict__ W1y, const float* __restrict__ b1y, const float* __restrict__ W2y,
    float* __restrict__ rpe_x, float* __restrict__ rpe_y)
{
    __shared__ float4 sW1i[512];   // {W1x[j], W1x[512+j], W1y[j], W1y[512+j]}
    __shared__ float2 sB1i[512];   // {b1x[j], b1y[j]}
    __shared__ float sW2x[4096], sW2y[4096];
    const int tid = threadIdx.x;
    for (int i = tid; i < 512; i += 256) {
        sW1i[i] = make_float4(W1x[i], W1x[512 + i], W1y[i], W1y[512 + i]);
        sB1i[i] = make_float2(b1x[i], b1y[i]);
    }
    for (int i = tid; i < 4096; i += 256) { sW2x[i] = W2x[i]; sW2y[i] = W2y[i]; }
    __syncthreads();

    const int gid = blockIdx.x * 256 + tid;
    const int pos = gid & 63;
    const int bq  = gid >> 6;
    const float4 r = *(const float4*)(ref2d + (size_t)bq * 4);
    const float pc = (pos + 0.5f) * 16.0f;
    const float dx0 = (r.x - r.z * 0.5f) - pc;
    const float dx1 = (r.x + r.z * 0.5f) - pc;
    const float dy0 = (r.y - r.w * 0.5f) - pc;
    const float dy1 = (r.y + r.w * 0.5f) - pc;

    float ax[8] = {}, ay[8] = {};
    const float4* w2xp = (const float4*)sW2x;
    const float4* w2yp = (const float4*)sW2y;
    #pragma unroll 2
    for (int j = 0; j < 512; ++j) {
        float4 w1 = sW1i[j];
        float2 bb = sB1i[j];
        float hx = fmaxf(fmaf(dx0, w1.x, fmaf(dx1, w1.y, bb.x)), 0.f);
        float hy = fmaxf(fmaf(dy0, w1.z, fmaf(dy1, w1.w, bb.y)), 0.f);
        float4 wx0 = w2xp[j * 2], wx1 = w2xp[j * 2 + 1];
        float4 wy0 = w2yp[j * 2], wy1 = w2yp[j * 2 + 1];
        ax[0] = fmaf(hx, wx0.x, ax[0]); ax[1] = fmaf(hx, wx0.y, ax[1]);
        ax[2] = fmaf(hx, wx0.z, ax[2]); ax[3] = fmaf(hx, wx0.w, ax[3]);
        ax[4] = fmaf(hx, wx1.x, ax[4]); ax[5] = fmaf(hx, wx1.y, ax[5]);
        ax[6] = fmaf(hx, wx1.z, ax[6]); ax[7] = fmaf(hx, wx1.w, ax[7]);
        ay[0] = fmaf(hy, wy0.x, ay[0]); ay[1] = fmaf(hy, wy0.y, ay[1]);
        ay[2] = fmaf(hy, wy0.z, ay[2]); ay[3] = fmaf(hy, wy0.w, ay[3]);
        ay[4] = fmaf(hy, wy1.x, ay[4]); ay[5] = fmaf(hy, wy1.y, ay[5]);
        ay[6] = fmaf(hy, wy1.z, ay[6]); ay[7] = fmaf(hy, wy1.w, ay[7]);
    }
    #pragma unroll
    for (int t = 0; t < 8; ++t) {
        rpe_x[(size_t)gid * 8 + t] = ax[t];
        rpe_y[(size_t)gid * 8 + t] = ay[t];
    }
}

// ---------------------------------------------------------------------------
// MFMA flash attention, 8-wave blocks: 32 q-rows x 4 key-splits, grid 480
// (-> 2 blocks/CU at 60 KB LDS; independent barrier domains overlap stalls).
// P-store uses XOR swizzle gphys = grp ^ (m>>2): 4-way -> 2-way (free).
// ---------------------------------------------------------------------------
__global__ __launch_bounds__(512, 4) void attn_mfma_kernel(
    const unsigned short* __restrict__ qb16, const unsigned short* __restrict__ kb16,
    const unsigned short* __restrict__ vb16,
    const float* __restrict__ rpe_x, const float* __restrict__ rpe_y,
    const unsigned char* __restrict__ mask, float* __restrict__ xout)
{
    __shared__ short skf[4 * 2048];      // K frags per ksplit; reused as obuf at end
    __shared__ short svt[4 * 2304];      // V^T per ksplit: [32 d][72 stride]
    __shared__ short spb[8 * 544];       // P buf per wave (XOR-swizzled groups)
    __shared__ float rx[32 * 65];
    __shared__ float ry[32 * 65];
    __shared__ float sm[8][16], sl[8][16], sLf[32];

    const int tid = threadIdx.x;
    const int qb = blockIdx.x, h = blockIdx.y, b = blockIdx.z;
    const int q0 = qb * 32;
    const int w = tid >> 6, l = tid & 63;
    const int qsub = w >> 2, g = w & 3;
    const int quad = l >> 4, l15 = l & 15;

    const unsigned short* qg = qb16 + (size_t)(b * 8 + h) * 960 * 32;
    const unsigned short* kg = kb16 + (size_t)(b * 8 + h) * 4096 * 32;
    const unsigned short* vg = vb16 + (size_t)(b * 8 + h) * 4096 * 32;

    for (int i = tid; i < 2048; i += 512) {
        int qq = q0 + (i >> 6), pos = i & 63;
        float vx = 0.f, vy = 0.f;
        if (qq < NQ_) {
            size_t base = ((size_t)(b * NQ_ + qq) * 64 + pos) * 8 + h;
            vx = rpe_x[base];
            vy = rpe_y[base];
        }
        rx[(i >> 6) * 65 + pos] = vx;
        ry[(i >> 6) * 65 + pos] = vy;
    }

    s16x8 qa = *(const s16x8*)(qg + (size_t)(q0 + qsub * 16 + l15) * 32 + quad * 8);

    // staging roles: sg = which ksplit's chunk, role 0 = K (4 frag uint4s),
    // role 1 = V (4 d-seg uint4s -> 32 transposed b16 writes)
    const int sg = tid >> 7, role = (tid >> 6) & 1, stl = tid & 63;
    const unsigned short* src = role ? vg : kg;
    int eoff[4];
    #pragma unroll
    for (int t = 0; t < 4; ++t)
        eoff[t] = role ? (stl * 32 + t * 8)
                       : ((t * 16 + (stl & 15)) * 32 + (stl >> 4) * 8);

    uint4 pf[4];
    {
        size_t cb = (size_t)(sg * 16) * 64 * 32;
        #pragma unroll
        for (int t = 0; t < 4; ++t) pf[t] = *(const uint4*)(src + cb + eoff[t]);
    }

    __syncthreads();   // rx/ry visible
    float rxr[4][4];
    #pragma unroll
    for (int t = 0; t < 4; ++t)
        #pragma unroll
        for (int r = 0; r < 4; ++r)
            rxr[t][r] = rx[(qsub * 16 + quad * 4 + r) * 65 + t * 16 + l15];

    float mrow[4] = {-INFINITY, -INFINITY, -INFINITY, -INFINITY};
    float lrow[4] = {0.f, 0.f, 0.f, 0.f};
    f32x4 acc0 = {0.f, 0.f, 0.f, 0.f}, acc1 = {0.f, 0.f, 0.f, 0.f};
    short* pw = spb + w * 544;

    for (int i = 0; i < 16; ++i) {
        __syncthreads();
        if (role == 0) {
            #pragma unroll
            for (int t = 0; t < 4; ++t)
                *(uint4*)(skf + sg * 2048 + (t * 64 + stl) * 8) = pf[t];
        } else {
            short* vtw = svt + sg * 2304;
            #pragma unroll
            for (int s = 0; s < 4; ++s) {
                const unsigned short* pv = (const unsigned short*)&pf[s];
                #pragma unroll
                for (int j = 0; j < 8; ++j)
                    vtw[(s * 8 + j) * 72 + stl] = (short)pv[j];
            }
        }
        __syncthreads();

        {
            int inext = (i + 1 < 16) ? i + 1 : 15;
            size_t cb = (size_t)(sg * 16 + inext) * 64 * 32;
            #pragma unroll
            for (int t = 0; t < 4; ++t) pf[t] = *(const uint4*)(src + cb + eoff[t]);
        }

        const int cgc = g * 16 + i;
        const short* kf = skf + g * 2048;

        f32x4 sc[4];
        #pragma unroll
        for (int t = 0; t < 4; ++t) {
            s16x8 kb = *(const s16x8*)(kf + (t * 64 + l) * 8);
            f32x4 z = {0.f, 0.f, 0.f, 0.f};
            sc[t] = __builtin_amdgcn_mfma_f32_16x16x32_bf16(qa, kb, z, 0, 0, 0);
        }
        float ryv[4];
        #pragma unroll
        for (int r = 0; r < 4; ++r)
            ryv[r] = ry[(qsub * 16 + quad * 4 + r) * 65 + cgc];
        #pragma unroll
        for (int t = 0; t < 4; ++t) {
            float mk = mask[(size_t)b * N_ + cgc * 64 + t * 16 + l15] ? -100.f : 0.f;
            #pragma unroll
            for (int r = 0; r < 4; ++r)
                sc[t][r] += rxr[t][r] + ryv[r] + mk;
        }
        float cm[4];
        #pragma unroll
        for (int r = 0; r < 4; ++r)
            cm[r] = fmaxf(fmaxf(sc[0][r], sc[1][r]), fmaxf(sc[2][r], sc[3][r]));
        #pragma unroll
        for (int off = 1; off < 16; off <<= 1)
            #pragma unroll
            for (int r = 0; r < 4; ++r)
                cm[r] = fmaxf(cm[r], __shfl_xor(cm[r], off, 16));
        float al[4];
        #pragma unroll
        for (int r = 0; r < 4; ++r) {
            float mnew = fmaxf(mrow[r], cm[r]);
            al[r] = __expf(mrow[r] - mnew);
            mrow[r] = mnew;
            lrow[r] *= al[r];
            acc0[r] *= al[r];
            acc1[r] *= al[r];
        }
        #pragma unroll
        for (int t = 0; t < 4; ++t)
            #pragma unroll
            for (int r = 0; r < 4; ++r)
                sc[t][r] = __expf(sc[t][r] - mrow[r]);
        float rs[4];
        #pragma unroll
        for (int r = 0; r < 4; ++r)
            rs[r] = (sc[0][r] + sc[1][r]) + (sc[2][r] + sc[3][r]);
        #pragma unroll
        for (int off = 1; off < 16; off <<= 1)
            #pragma unroll
            for (int r = 0; r < 4; ++r)
                rs[r] += __shfl_xor(rs[r], off, 16);
        #pragma unroll
        for (int r = 0; r < 4; ++r)
            lrow[r] += rs[r];

        const short* vt = svt + g * 2304;
        #pragma unroll
        for (int hh = 0; hh < 2; ++hh) {
            #pragma unroll
            for (int tt = 0; tt < 2; ++tt) {
                int t = hh * 2 + tt;
                int grp = tt * 2 + (l15 >> 3);
                int gphys = grp ^ quad;               // XOR swizzle: 2-way banks
                #pragma unroll
                for (int r = 0; r < 4; ++r)
                    pw[(gphys * 17 + quad * 4 + r) * 8 + (l15 & 7)] = f2bf(sc[t][r]);
            }
            int gph_r = quad ^ (l15 >> 2);
            s16x8 pa  = *(const s16x8*)(pw + (gph_r * 17 + l15) * 8);
            s16x8 vb0 = *(const s16x8*)(vt + (l15)      * 72 + hh * 32 + quad * 8);
            s16x8 vb1 = *(const s16x8*)(vt + (16 + l15) * 72 + hh * 32 + quad * 8);
            acc0 = __builtin_amdgcn_mfma_f32_16x16x32_bf16(pa, vb0, acc0, 0, 0, 0);
            acc1 = __builtin_amdgcn_mfma_f32_16x16x32_bf16(pa, vb1, acc1, 0, 0, 0);
        }
    }

    __syncthreads();
    if (l15 == 0) {
        #pragma unroll
        for (int r = 0; r < 4; ++r) {
            sm[w][quad * 4 + r] = mrow[r];
            sl[w][quad * 4 + r] = lrow[r];
        }
    }
    __syncthreads();
    float wgt[4], L4[4];
    #pragma unroll
    for (int r = 0; r < 4; ++r) {
        int qrow = quad * 4 + r;
        float mm = -INFINITY;
        #pragma unroll
        for (int gg = 0; gg < 4; ++gg) mm = fmaxf(mm, sm[qsub * 4 + gg][qrow]);
        float LL = 0.f;
        #pragma unroll
        for (int gg = 0; gg < 4; ++gg)
            LL += __expf(sm[qsub * 4 + gg][qrow] - mm) * sl[qsub * 4 + gg][qrow];
        wgt[r] = __expf(mrow[r] - mm);
        L4[r] = LL;
    }
    if (g == 0 && l15 == 0) {
        #pragma unroll
        for (int r = 0; r < 4; ++r) sLf[qsub * 16 + quad * 4 + r] = L4[r];
    }

    float* obuf = (float*)skf;    // 32x33 fp32 = 4.2 KB
    for (int gg = 0; gg < 4; ++gg) {
        if (g == gg) {
            #pragma unroll
            for (int r = 0; r < 4; ++r) {
                int idx = (qsub * 16 + quad * 4 + r) * 33 + l15;
                float v0 = wgt[r] * acc0[r];
                float v1 = wgt[r] * acc1[r];
                if (gg == 0) { obuf[idx] = v0; obuf[idx + 16] = v1; }
                else         { obuf[idx] += v0; obuf[idx + 16] += v1; }
            }
        }
        __syncthreads();
    }

    for (int i = tid; i < 1024; i += 512) {
        int ql = i >> 5, d = i & 31;
        int qq = q0 + ql;
        if (qq < NQ_)
            xout[(size_t)(b * NQ_ + qq) * 256 + h * 32 + d] = obuf[ql * 33 + d] / sLf[ql];
    }
}

// ---------------------------------------------------------------------------
extern "C" void kernel_launch(void* const* d_in, const int* in_sizes, int n_in,
                              void* d_out, int out_size, void* d_ws, size_t ws_size,
                              hipStream_t stream)
{
    const float* query = (const float*)d_in[1];
    const float* ref2d = (const float*)d_in[2];
    const float* kin   = (const float*)d_in[3];
    const float* vin   = (const float*)d_in[4];
    const unsigned char* mask = (const unsigned char*)d_in[6];
    const float* W1x = (const float*)d_in[7];
    const float* b1x = (const float*)d_in[8];
    const float* W2x = (const float*)d_in[9];
    const float* W1y = (const float*)d_in[10];
    const float* b1y = (const float*)d_in[11];
    const float* W2y = (const float*)d_in[12];
    const float* Wq  = (const float*)d_in[13];
    const float* bq  = (const float*)d_in[14];
    const float* Wk  = (const float*)d_in[15];
    const float* bk  = (const float*)d_in[16];
    const float* Wv  = (const float*)d_in[17];
    const float* bv  = (const float*)d_in[18];
    const float* Wp  = (const float*)d_in[19];
    const float* bp  = (const float*)d_in[20];

    // Workspace ~19 MB (proven-safe footprint is 27.8 MB)
    char* wsb = (char*)d_ws;
    unsigned short* qbf = (unsigned short*)wsb;                        // 983040 B
    unsigned short* kbf = (unsigned short*)(wsb + 983040);             // 4194304 B
    unsigned short* vbf = (unsigned short*)(wsb + 983040 + 4194304);   // 4194304 B
    unsigned short* wtb = (unsigned short*)(wsb + 983040 + 2 * 4194304); // 393216 B
    float* rxws = (float*)(wsb + 983040 + 2 * 4194304 + 393216);       // 921600 f32
    float* ryws = rxws + 921600;
    float* xws  = ryws + 921600;                                       // 460800 f32
    float* out  = (float*)d_out;

    const float scale = 1.0f / sqrtf(32.0f);

    wtconv_kernel<<<dim3(256, 3), 256, 0, stream>>>(Wq, Wk, Wv, wtb);
    gemm_mfma_bf16h<<<dim3(29, 4),  256, 0, stream>>>(query, wtb,           bq, qbf, 1800, scale, 900, 960);
    gemm_mfma_bf16h<<<dim3(128, 4), 256, 0, stream>>>(kin,   wtb + 65536,   bk, kbf, 8192, 1.0f, 4096, 4096);
    gemm_mfma_bf16h<<<dim3(128, 4), 256, 0, stream>>>(vin,   wtb + 131072,  bv, vbf, 8192, 1.0f, 4096, 4096);
    rpe_kernel<<<450, 256, 0, stream>>>(ref2d, W1x, b1x, W2x, W1y, b1y, W2y, rxws, ryws);
    attn_mfma_kernel<<<dim3(30, 8, B_), 512, 0, stream>>>(qbf, kbf, vbf, rxws, ryws, mask, xws);
    gemm_bias_kernel<<<dim3(29, 4), 256, 0, stream>>>(xws, Wp, bp, out, 1800, 1.0f);
}